// Round 2
// baseline (18146.625 us; speedup 1.0000x reference)
//
#include <hip/hip_runtime.h>

#define TT 512
#define BB 256
#define II 128
#define HH 256

typedef __attribute__((ext_vector_type(8))) short short8;
typedef __attribute__((ext_vector_type(4))) float floatx4;
typedef __attribute__((ext_vector_type(4))) float fvec4;

// ws layout (shorts): wih0[3H*I], whh0[3H*H], wih1[3H*H], whh1[3H*H]
#define OFF_WIH0 0
#define OFF_WHH0 (OFF_WIH0 + 3 * HH * II)
#define OFF_WIH1 (OFF_WHH0 + 3 * HH * HH)
#define OFF_WHH1 (OFF_WIH1 + 3 * HH * HH)
#define W_TOTAL (OFF_WHH1 + 3 * HH * HH)

__device__ __forceinline__ short f2bf(float f) {
  unsigned u = __builtin_bit_cast(unsigned, f);
  u = u + 0x7fffu + ((u >> 16) & 1u);  // round-to-nearest-even
  return (short)(u >> 16);
}
__device__ __forceinline__ float fast_sigmoid(float x) {
  return __fdividef(1.0f, 1.0f + __expf(-x));
}
__device__ __forceinline__ float fast_tanh(float x) {
  return 1.0f - __fdividef(2.0f, 1.0f + __expf(2.0f * x));
}
__device__ __forceinline__ short8 cvt8(const float* __restrict__ p) {
  fvec4 lo = *(const fvec4*)p;
  fvec4 hi = *(const fvec4*)(p + 4);
  short8 r;
  r[0] = f2bf(lo[0]); r[1] = f2bf(lo[1]); r[2] = f2bf(lo[2]); r[3] = f2bf(lo[3]);
  r[4] = f2bf(hi[0]); r[5] = f2bf(hi[1]); r[6] = f2bf(hi[2]); r[7] = f2bf(hi[3]);
  return r;
}

// fp32 -> bf16 weight conversion into ws (graph-safe, same work every call)
__global__ __launch_bounds__(256) void cvt_weights(
    const float* __restrict__ w0, const float* __restrict__ w1,
    const float* __restrict__ w2, const float* __restrict__ w3,
    short* __restrict__ out) {
  int i = blockIdx.x * 256 + threadIdx.x;
  if (i >= W_TOTAL) return;
  float v;
  if (i < OFF_WHH0)       v = w0[i - OFF_WIH0];
  else if (i < OFF_WIH1)  v = w1[i - OFF_WHH0];
  else if (i < OFF_WHH1)  v = w2[i - OFF_WIH1];
  else                    v = w3[i - OFF_WHH1];
  out[i] = f2bf(v);
}

// Fused 2-layer GRU + FC. Grid: 16 blocks (batch tiles of 16), 512 thr = 8 waves.
// Wave w owns hidden slice [w*32, w*32+32). Both layers advance in lockstep per
// step t; h1[t] lives only in LDS. fp32 master h state in registers; MFMA in bf16.
__global__ __launch_bounds__(512) void gru_fused(
    const float* __restrict__ x, const short* __restrict__ wb,
    const float* __restrict__ bih0, const float* __restrict__ bhh0,
    const float* __restrict__ bih1, const float* __restrict__ bhh1,
    const float* __restrict__ Wfc, const float* __restrict__ bfc,
    float* __restrict__ out) {
  constexpr int LDH = HH + 8;  // +8 bf16 pad: b128 rows land 2-way on banks (free)
  const int tid = threadIdx.x;
  const int lane = tid & 63;
  const int w = tid >> 6;
  const int quad = lane >> 4;
  const int col = lane & 15;
  const int b0 = blockIdx.x * 16;
  const int jw = w * 32;

  __shared__ __align__(16) short h1buf[2][16][LDH];
  __shared__ __align__(16) short h2buf[2][16][LDH];
  for (int i = tid; i < 2 * 16 * LDH; i += 512) {
    (&h1buf[0][0][0])[i] = 0;
    (&h2buf[0][0][0])[i] = 0;
  }

  const short* wih0 = wb + OFF_WIH0;
  const short* whh0 = wb + OFF_WHH0;
  const short* wih1 = wb + OFF_WIH1;
  const short* whh1 = wb + OFF_WHH1;

  // Per-lane constants: biases folded into acc init, weight-row base offsets.
  float c0r[2], c0z[2], c0ni[2], c0nh[2];
  float c1r[2], c1z[2], c1ni[2], c1nh[2];
  int rI0[3][2], rH0[3][2], rI1[3][2], rH1[3][2];
#pragma unroll
  for (int s = 0; s < 2; ++s) {
    int j = jw + s * 16 + col;
    c0r[s] = bih0[j] + bhh0[j];
    c0z[s] = bih0[HH + j] + bhh0[HH + j];
    c0ni[s] = bih0[2 * HH + j];
    c0nh[s] = bhh0[2 * HH + j];
    c1r[s] = bih1[j] + bhh1[j];
    c1z[s] = bih1[HH + j] + bhh1[HH + j];
    c1ni[s] = bih1[2 * HH + j];
    c1nh[s] = bhh1[2 * HH + j];
#pragma unroll
    for (int g = 0; g < 3; ++g) {
      rI0[g][s] = (g * HH + j) * II + quad * 8;
      rH0[g][s] = (g * HH + j) * HH + quad * 8;
      rI1[g][s] = (g * HH + j) * HH + quad * 8;
      rH1[g][s] = (g * HH + j) * HH + quad * 8;
    }
  }

  float h1reg[2][4] = {{0.f, 0.f, 0.f, 0.f}, {0.f, 0.f, 0.f, 0.f}};
  float h2reg[2][4] = {{0.f, 0.f, 0.f, 0.f}, {0.f, 0.f, 0.f, 0.f}};
  __syncthreads();

#pragma unroll 1
  for (int t = 0; t < TT; ++t) {
    // ================= layer 0 =================
    const short* cur1 = &h1buf[t & 1][0][0];
    short* nxt1 = &h1buf[(t + 1) & 1][0][0];
    floatx4 ar[2], az[2], ani[2], anh[2];
#pragma unroll
    for (int s = 0; s < 2; ++s) {
      ar[s] = floatx4{c0r[s], c0r[s], c0r[s], c0r[s]};
      az[s] = floatx4{c0z[s], c0z[s], c0z[s], c0z[s]};
      ani[s] = floatx4{c0ni[s], c0ni[s], c0ni[s], c0ni[s]};
      anh[s] = floatx4{c0nh[s], c0nh[s], c0nh[s], c0nh[s]};
    }
    // ih: A = x[t] rows (fp32 -> bf16 cvt on the fly), B = W_ih0 rows (bf16, L2)
    const float* xrow = x + ((size_t)t * BB + b0 + col) * II + quad * 8;
#pragma unroll
    for (int kk = 0; kk < II / 32; ++kk) {
      short8 a = cvt8(xrow + kk * 32);
#pragma unroll
      for (int s = 0; s < 2; ++s) {
        short8 br = *(const short8*)(wih0 + rI0[0][s] + kk * 32);
        short8 bz = *(const short8*)(wih0 + rI0[1][s] + kk * 32);
        short8 bn = *(const short8*)(wih0 + rI0[2][s] + kk * 32);
        ar[s] = __builtin_amdgcn_mfma_f32_16x16x32_bf16(a, br, ar[s], 0, 0, 0);
        az[s] = __builtin_amdgcn_mfma_f32_16x16x32_bf16(a, bz, az[s], 0, 0, 0);
        ani[s] = __builtin_amdgcn_mfma_f32_16x16x32_bf16(a, bn, ani[s], 0, 0, 0);
      }
    }
    // hh: A = h1[t-1] from LDS, B = W_hh0 rows
#pragma unroll
    for (int kk = 0; kk < HH / 32; ++kk) {
      short8 a = *(const short8*)(cur1 + col * LDH + kk * 32 + quad * 8);
#pragma unroll
      for (int s = 0; s < 2; ++s) {
        short8 br = *(const short8*)(whh0 + rH0[0][s] + kk * 32);
        short8 bz = *(const short8*)(whh0 + rH0[1][s] + kk * 32);
        short8 bn = *(const short8*)(whh0 + rH0[2][s] + kk * 32);
        ar[s] = __builtin_amdgcn_mfma_f32_16x16x32_bf16(a, br, ar[s], 0, 0, 0);
        az[s] = __builtin_amdgcn_mfma_f32_16x16x32_bf16(a, bz, az[s], 0, 0, 0);
        anh[s] = __builtin_amdgcn_mfma_f32_16x16x32_bf16(a, bn, anh[s], 0, 0, 0);
      }
    }
    // elementwise; D layout: batch row = quad*4+i, hidden col = lane&15
#pragma unroll
    for (int s = 0; s < 2; ++s) {
      int j = jw + s * 16 + col;
#pragma unroll
      for (int i = 0; i < 4; ++i) {
        float r = fast_sigmoid(ar[s][i]);
        float z = fast_sigmoid(az[s][i]);
        float n = fast_tanh(ani[s][i] + r * anh[s][i]);
        float hn = n + z * (h1reg[s][i] - n);
        h1reg[s][i] = hn;
        nxt1[(quad * 4 + i) * LDH + j] = f2bf(hn);
      }
    }
    __syncthreads();  // h1[t] complete before layer 1 consumes it

    // ================= layer 1 =================
    const short* cur2 = &h2buf[t & 1][0][0];
    short* nxt2 = &h2buf[(t + 1) & 1][0][0];
#pragma unroll
    for (int s = 0; s < 2; ++s) {
      ar[s] = floatx4{c1r[s], c1r[s], c1r[s], c1r[s]};
      az[s] = floatx4{c1z[s], c1z[s], c1z[s], c1z[s]};
      ani[s] = floatx4{c1ni[s], c1ni[s], c1ni[s], c1ni[s]};
      anh[s] = floatx4{c1nh[s], c1nh[s], c1nh[s], c1nh[s]};
    }
    // ih: A = h1[t] from LDS (just written), B = W_ih1
#pragma unroll
    for (int kk = 0; kk < HH / 32; ++kk) {
      short8 a = *(const short8*)(nxt1 + col * LDH + kk * 32 + quad * 8);
#pragma unroll
      for (int s = 0; s < 2; ++s) {
        short8 br = *(const short8*)(wih1 + rI1[0][s] + kk * 32);
        short8 bz = *(const short8*)(wih1 + rI1[1][s] + kk * 32);
        short8 bn = *(const short8*)(wih1 + rI1[2][s] + kk * 32);
        ar[s] = __builtin_amdgcn_mfma_f32_16x16x32_bf16(a, br, ar[s], 0, 0, 0);
        az[s] = __builtin_amdgcn_mfma_f32_16x16x32_bf16(a, bz, az[s], 0, 0, 0);
        ani[s] = __builtin_amdgcn_mfma_f32_16x16x32_bf16(a, bn, ani[s], 0, 0, 0);
      }
    }
    // hh: A = h2[t-1] from LDS, B = W_hh1
#pragma unroll
    for (int kk = 0; kk < HH / 32; ++kk) {
      short8 a = *(const short8*)(cur2 + col * LDH + kk * 32 + quad * 8);
#pragma unroll
      for (int s = 0; s < 2; ++s) {
        short8 br = *(const short8*)(whh1 + rH1[0][s] + kk * 32);
        short8 bz = *(const short8*)(whh1 + rH1[1][s] + kk * 32);
        short8 bn = *(const short8*)(whh1 + rH1[2][s] + kk * 32);
        ar[s] = __builtin_amdgcn_mfma_f32_16x16x32_bf16(a, br, ar[s], 0, 0, 0);
        az[s] = __builtin_amdgcn_mfma_f32_16x16x32_bf16(a, bz, az[s], 0, 0, 0);
        anh[s] = __builtin_amdgcn_mfma_f32_16x16x32_bf16(a, bn, anh[s], 0, 0, 0);
      }
    }
#pragma unroll
    for (int s = 0; s < 2; ++s) {
      int j = jw + s * 16 + col;
#pragma unroll
      for (int i = 0; i < 4; ++i) {
        float r = fast_sigmoid(ar[s][i]);
        float z = fast_sigmoid(az[s][i]);
        float n = fast_tanh(ani[s][i] + r * anh[s][i]);
        float hn = n + z * (h2reg[s][i] - n);
        h2reg[s][i] = hn;
        nxt2[(quad * 4 + i) * LDH + j] = f2bf(hn);
      }
    }
    __syncthreads();  // h1/h2 buffers consistent before next step
  }

  // ================= FC epilogue: out = h2_last @ Wfc^T + bfc =================
  const short* hf = &h2buf[TT & 1][0][0];  // last written buffer (TT even -> [0])
  floatx4 acc[2];
#pragma unroll
  for (int s = 0; s < 2; ++s) {
    float b = bfc[jw + s * 16 + col];
    acc[s] = floatx4{b, b, b, b};
  }
#pragma unroll
  for (int kk = 0; kk < HH / 32; ++kk) {
    short8 a = *(const short8*)(hf + col * LDH + kk * 32 + quad * 8);
#pragma unroll
    for (int s = 0; s < 2; ++s) {
      short8 bfrag = cvt8(Wfc + (jw + s * 16 + col) * HH + kk * 32 + quad * 8);
      acc[s] = __builtin_amdgcn_mfma_f32_16x16x32_bf16(a, bfrag, acc[s], 0, 0, 0);
    }
  }
#pragma unroll
  for (int s = 0; s < 2; ++s)
#pragma unroll
    for (int i = 0; i < 4; ++i)
      out[(size_t)(b0 + quad * 4 + i) * HH + jw + s * 16 + col] = acc[s][i];
}

extern "C" void kernel_launch(void* const* d_in, const int* in_sizes, int n_in,
                              void* d_out, int out_size, void* d_ws,
                              size_t ws_size, hipStream_t stream) {
  const float* x = (const float*)d_in[0];
  const float* Wih0 = (const float*)d_in[1];
  const float* Whh0 = (const float*)d_in[2];
  const float* bih0 = (const float*)d_in[3];
  const float* bhh0 = (const float*)d_in[4];
  const float* Wih1 = (const float*)d_in[5];
  const float* Whh1 = (const float*)d_in[6];
  const float* bih1 = (const float*)d_in[7];
  const float* bhh1 = (const float*)d_in[8];
  const float* Wfc = (const float*)d_in[9];
  const float* bfc = (const float*)d_in[10];

  short* wb = (short*)d_ws;  // 1.38 MB of bf16 weights

  cvt_weights<<<(W_TOTAL + 255) / 256, 256, 0, stream>>>(Wih0, Whh0, Wih1, Whh1, wb);
  gru_fused<<<16, 512, 0, stream>>>(x, wb, bih0, bhh0, bih1, bhh1, Wfc, bfc,
                                    (float*)d_out);
}

// Round 3
// 6590.547 us; speedup vs baseline: 2.7534x; 2.7534x over previous
//
#include <hip/hip_runtime.h>

#define TT 512
#define BB 256
#define II 128
#define HH 256

typedef __attribute__((ext_vector_type(8))) short short8;
typedef __attribute__((ext_vector_type(4))) float floatx4;
typedef __attribute__((ext_vector_type(4))) float fvec4;

// ws layout (shorts): bf16 weights, then h1g[2][B][H], h2g[2][B][H], then flags.
#define OFF_WIH0 0
#define OFF_WHH0 (OFF_WIH0 + 3 * HH * II)
#define OFF_WIH1 (OFF_WHH0 + 3 * HH * HH)
#define OFF_WHH1 (OFF_WIH1 + 3 * HH * HH)
#define W_TOTAL (OFF_WHH1 + 3 * HH * HH)        // 688128 shorts
#define H1G_OFF W_TOTAL                          // 2*B*H shorts
#define H2G_OFF (H1G_OFF + 2 * BB * HH)
#define WS_SHORTS (H2G_OFF + 2 * BB * HH)        // 950272 shorts
#define FLAGS_OFF_BYTES (WS_SHORTS * 2)          // 1900544 B
#define NGROUP 16
#define FLAG_STRIDE 32                           // uints (128 B, no false sharing)

__device__ __forceinline__ short f2bf(float f) {
  unsigned u = __builtin_bit_cast(unsigned, f);
  u = u + 0x7fffu + ((u >> 16) & 1u);
  return (short)(u >> 16);
}
__device__ __forceinline__ float fast_sigmoid(float x) {
  return __fdividef(1.0f, 1.0f + __expf(-x));
}
__device__ __forceinline__ float fast_tanh(float x) {
  return 1.0f - __fdividef(2.0f, 1.0f + __expf(2.0f * x));
}
__device__ __forceinline__ short8 cvt8(const float* __restrict__ p) {
  fvec4 lo = *(const fvec4*)p;
  fvec4 hi = *(const fvec4*)(p + 4);
  short8 r;
  r[0] = f2bf(lo[0]); r[1] = f2bf(lo[1]); r[2] = f2bf(lo[2]); r[3] = f2bf(lo[3]);
  r[4] = f2bf(hi[0]); r[5] = f2bf(hi[1]); r[6] = f2bf(hi[2]); r[7] = f2bf(hi[3]);
  return r;
}

__global__ __launch_bounds__(256) void cvt_weights(
    const float* __restrict__ w0, const float* __restrict__ w1,
    const float* __restrict__ w2, const float* __restrict__ w3,
    short* __restrict__ out) {
  int i = blockIdx.x * 256 + threadIdx.x;
  if (i >= W_TOTAL) return;
  float v;
  if (i < OFF_WHH0)      v = w0[i - OFF_WIH0];
  else if (i < OFF_WIH1) v = w1[i - OFF_WHH0];
  else if (i < OFF_WHH1) v = w2[i - OFF_WIH1];
  else                   v = w3[i - OFF_WHH1];
  out[i] = f2bf(v);
}

// Zero the h exchange buffers + flags (ws is poisoned 0xAA before each launch).
__global__ __launch_bounds__(256) void init_state(unsigned* __restrict__ hz,
                                                  unsigned* __restrict__ flags) {
  int i = blockIdx.x * 256 + threadIdx.x;
  if (i < 2 * BB * HH) hz[i] = 0u;  // 2 buffers * 2 parities * B*H shorts = 2*B*H uints... (4*B*H shorts = 2*B*H uints per buffer pair handled below)
  if (i < NGROUP * FLAG_STRIDE) flags[i] = 0u;
}

// Persistent cooperative GRU: 256 blocks = (bt 0..15) x (ht 0..15), 384 thr = 6 waves.
// Wave w = (layer = w/3, gate = w%3) owns 16 output cols [ht*16, ht*16+16) of its
// gate; its weight B-fragments live in VGPRs for the whole kernel.
// Phase p (0..512): computes h1[p] (uses h1[p-1]) and h2[p-1] (uses h1[p-1],
// h2[p-2]); then one exchange/sync per group of 16 blocks.
__global__ __launch_bounds__(384) void gru_sync(
    const float* __restrict__ x, const short* __restrict__ wb,
    const float* __restrict__ bih0, const float* __restrict__ bhh0,
    const float* __restrict__ bih1, const float* __restrict__ bhh1,
    const float* __restrict__ Wfc, const float* __restrict__ bfc,
    short* __restrict__ h1g, short* __restrict__ h2g,
    unsigned* __restrict__ flags, float* __restrict__ out) {
  const int tid = threadIdx.x;
  const int lane = tid & 63;
  const int w = tid >> 6;        // 0..5
  const int quad = lane >> 4;
  const int col = lane & 15;
  const int bt = blockIdx.x & 15;   // group: same bt -> same XCD class (%8 swizzle)
  const int ht = blockIdx.x >> 4;
  const int layer = w / 3;
  const int gate = w % 3;
  const int j = ht * 16 + col;   // this lane's output column

  __shared__ float gtIH[6][16][20];
  __shared__ float gtHH[6][16][20];

  // ---- preload weight fragments into registers (uniform 16 frags/wave) ----
  const short* wih = wb + (layer ? OFF_WIH1 : OFF_WIH0);
  const short* whh = wb + (layer ? OFF_WHH1 : OFF_WHH0);
  const int KI = layer ? HH : II;
  short8 wf[16];
#pragma unroll
  for (int f = 0; f < 8; ++f) {
    if (f * 32 < KI)
      wf[f] = *(const short8*)(wih + (gate * HH + j) * KI + f * 32 + quad * 8);
    else
      wf[f] = short8{0, 0, 0, 0, 0, 0, 0, 0};
  }
#pragma unroll
  for (int f = 0; f < 8; ++f)
    wf[8 + f] = *(const short8*)(whh + (gate * HH + j) * HH + f * 32 + quad * 8);

  // Bias folding: r/z -> both biases in IH acc; n -> keep separate (r* semantics).
  const float* bihL = layer ? bih1 : bih0;
  const float* bhhL = layer ? bhh1 : bhh0;
  float bI, bH;
  if (gate == 2) { bI = bihL[2 * HH + j]; bH = bhhL[2 * HH + j]; }
  else           { bI = bihL[gate * HH + j] + bhhL[gate * HH + j]; bH = 0.f; }

  // fp32 master h, thread-stable mapping.
  float h1m = 0.f, h2m = 0.f;
  const int eb1 = tid >> 4;          // L0 (tid<256): batch row, col = tid&15
  const int eb2 = (tid - 128) >> 4;  // L1 (tid>=128)
  const int ej = tid & 15;

  unsigned* cnt = flags + bt * FLAG_STRIDE;
  const int arow = (bt * 16 + col) * HH;

  for (int p = 0; p <= TT; ++p) {
    if (p > 0 && tid == 0) {
      unsigned tgt = 16u * (unsigned)p;
      int guard = 0;
      while (__hip_atomic_load(cnt, __ATOMIC_RELAXED, __HIP_MEMORY_SCOPE_AGENT) <
                 tgt &&
             guard < (1 << 18))
        ++guard;
      __threadfence();  // acquire: invalidate stale L1/L2 before anyone reads
    }
    __syncthreads();

    const short* h1p = h1g + ((p + 1) & 1) * BB * HH;  // h1[p-1]
    const short* h2p = h2g + (p & 1) * BB * HH;        // h2[p-2]

    // ---- A fragments ----
    short8 aih[8], ahh[8];
    if (layer == 0) {
      int px = p < TT ? p : TT - 1;  // p==TT: L0 result unused, stay in bounds
      const float* xr = x + ((size_t)px * BB + bt * 16 + col) * II + quad * 8;
#pragma unroll
      for (int f = 0; f < 4; ++f) aih[f] = cvt8(xr + f * 32);
#pragma unroll
      for (int f = 4; f < 8; ++f) aih[f] = aih[0];  // B is zero for these
#pragma unroll
      for (int f = 0; f < 8; ++f)
        ahh[f] = *(const short8*)(h1p + arow + f * 32 + quad * 8);
    } else {
#pragma unroll
      for (int f = 0; f < 8; ++f)
        aih[f] = *(const short8*)(h1p + arow + f * 32 + quad * 8);
#pragma unroll
      for (int f = 0; f < 8; ++f)
        ahh[f] = *(const short8*)(h2p + arow + f * 32 + quad * 8);
    }

    // ---- 16 MFMA: two independent 8-chains ----
    floatx4 aI = floatx4{bI, bI, bI, bI};
    floatx4 aH = floatx4{bH, bH, bH, bH};
#pragma unroll
    for (int f = 0; f < 8; ++f) {
      aI = __builtin_amdgcn_mfma_f32_16x16x32_bf16(aih[f], wf[f], aI, 0, 0, 0);
      aH = __builtin_amdgcn_mfma_f32_16x16x32_bf16(ahh[f], wf[8 + f], aH, 0, 0, 0);
    }
#pragma unroll
    for (int i = 0; i < 4; ++i) {
      gtIH[w][quad * 4 + i][col] = aI[i];
      gtHH[w][quad * 4 + i][col] = aH[i];
    }
    __syncthreads();

    // ---- elementwise + publish (bf16 slice stores) ----
    if (tid < 256 && p < TT) {
      float r = fast_sigmoid(gtIH[0][eb1][ej] + gtHH[0][eb1][ej]);
      float z = fast_sigmoid(gtIH[1][eb1][ej] + gtHH[1][eb1][ej]);
      float n = fast_tanh(gtIH[2][eb1][ej] + r * gtHH[2][eb1][ej]);
      float h = n + z * (h1m - n);
      h1m = h;
      h1g[(p & 1) * BB * HH + (bt * 16 + eb1) * HH + ht * 16 + ej] = f2bf(h);
    }
    if (tid >= 128 && p > 0) {
      float r = fast_sigmoid(gtIH[3][eb2][ej] + gtHH[3][eb2][ej]);
      float z = fast_sigmoid(gtIH[4][eb2][ej] + gtHH[4][eb2][ej]);
      float n = fast_tanh(gtIH[5][eb2][ej] + r * gtHH[5][eb2][ej]);
      float h = n + z * (h2m - n);
      h2m = h;
      h2g[((p + 1) & 1) * BB * HH + (bt * 16 + eb2) * HH + ht * 16 + ej] = f2bf(h);
    }
    __syncthreads();  // drains vmcnt: all threads' stores retired
    if (tid == 0) {
      __threadfence();  // release: write back dirty L2 lines for cross-XCD readers
      __hip_atomic_fetch_add(cnt, 1u, __ATOMIC_RELAXED, __HIP_MEMORY_SCOPE_AGENT);
    }
  }

  // ---- FC epilogue: out = h2[511] @ Wfc^T + bfc ----
  if (tid == 0) {
    unsigned tgt = 16u * (unsigned)(TT + 1);
    int guard = 0;
    while (__hip_atomic_load(cnt, __ATOMIC_RELAXED, __HIP_MEMORY_SCOPE_AGENT) <
               tgt &&
           guard < (1 << 18))
      ++guard;
    __threadfence();
  }
  __syncthreads();
  if (w == 0) {
    const short* hf = h2g + 1 * BB * HH;  // h2[511] parity = (512+1)&1 = 1
    float bb = bfc[j];
    floatx4 acc = floatx4{bb, bb, bb, bb};
#pragma unroll
    for (int f = 0; f < 8; ++f) {
      short8 a = *(const short8*)(hf + arow + f * 32 + quad * 8);
      short8 bfrag = cvt8(Wfc + j * HH + f * 32 + quad * 8);
      acc = __builtin_amdgcn_mfma_f32_16x16x32_bf16(a, bfrag, acc, 0, 0, 0);
    }
#pragma unroll
    for (int i = 0; i < 4; ++i)
      out[(size_t)(bt * 16 + quad * 4 + i) * HH + j] = acc[i];
  }
}

extern "C" void kernel_launch(void* const* d_in, const int* in_sizes, int n_in,
                              void* d_out, int out_size, void* d_ws,
                              size_t ws_size, hipStream_t stream) {
  const float* x = (const float*)d_in[0];
  const float* Wih0 = (const float*)d_in[1];
  const float* Whh0 = (const float*)d_in[2];
  const float* bih0 = (const float*)d_in[3];
  const float* bhh0 = (const float*)d_in[4];
  const float* Wih1 = (const float*)d_in[5];
  const float* Whh1 = (const float*)d_in[6];
  const float* bih1 = (const float*)d_in[7];
  const float* bhh1 = (const float*)d_in[8];
  const float* Wfc = (const float*)d_in[9];
  const float* bfc = (const float*)d_in[10];

  short* wb = (short*)d_ws;
  short* h1g = wb + H1G_OFF;
  short* h2g = wb + H2G_OFF;
  unsigned* flags = (unsigned*)((char*)d_ws + FLAGS_OFF_BYTES);
  unsigned* hz = (unsigned*)(wb + H1G_OFF);  // h1g+h2g = 4*B*H shorts = 2*B*H uints

  cvt_weights<<<(W_TOTAL + 255) / 256, 256, 0, stream>>>(Wih0, Whh0, Wih1, Whh1, wb);
  init_state<<<(2 * BB * HH + 255) / 256, 256, 0, stream>>>(hz, flags);
  gru_sync<<<256, 384, 0, stream>>>(x, wb, bih0, bhh0, bih1, bhh1, Wfc, bfc,
                                    h1g, h2g, flags, (float*)d_out);
}

// Round 4
// 1889.578 us; speedup vs baseline: 9.6035x; 3.4878x over previous
//
#include <hip/hip_runtime.h>

#define TT 512
#define BB 256
#define II 128
#define HH 256
#define LDH 264  // shorts/LDS row: 512B data + 16B pad (keeps 16B row alignment)

typedef __attribute__((ext_vector_type(8))) short short8;
typedef __attribute__((ext_vector_type(4))) float floatx4;
typedef __attribute__((ext_vector_type(4))) float fvec4;
typedef unsigned long long u64;

// ws layout (shorts): bf16 weights, h1g[2][B][H], h2g[2][B][H], then flags.
#define OFF_WIH0 0
#define OFF_WHH0 (OFF_WIH0 + 3 * HH * II)
#define OFF_WIH1 (OFF_WHH0 + 3 * HH * HH)
#define OFF_WHH1 (OFF_WIH1 + 3 * HH * HH)
#define W_TOTAL (OFF_WHH1 + 3 * HH * HH)
#define H1G_OFF W_TOTAL
#define H2G_OFF (H1G_OFF + 2 * BB * HH)
#define WS_SHORTS (H2G_OFF + 2 * BB * HH)
#define FLAGS_OFF_BYTES (WS_SHORTS * 2)
#define FLAG_STRIDE 32  // uints; 128B spacing kills false sharing

__device__ __forceinline__ short f2bf(float f) {
  unsigned u = __builtin_bit_cast(unsigned, f);
  u = u + 0x7fffu + ((u >> 16) & 1u);
  return (short)(u >> 16);
}
__device__ __forceinline__ float fast_sigmoid(float x) {
  return __fdividef(1.0f, 1.0f + __expf(-x));
}
__device__ __forceinline__ float fast_tanh(float x) {
  return 1.0f - __fdividef(2.0f, 1.0f + __expf(2.0f * x));
}
__device__ __forceinline__ short8 cvt8(const float* __restrict__ p) {
  fvec4 lo = *(const fvec4*)p;
  fvec4 hi = *(const fvec4*)(p + 4);
  short8 r;
  r[0] = f2bf(lo[0]); r[1] = f2bf(lo[1]); r[2] = f2bf(lo[2]); r[3] = f2bf(lo[3]);
  r[4] = f2bf(hi[0]); r[5] = f2bf(hi[1]); r[6] = f2bf(hi[2]); r[7] = f2bf(hi[3]);
  return r;
}
__device__ __forceinline__ u64 ld_sc1(const u64* p) {
  return __hip_atomic_load(p, __ATOMIC_RELAXED, __HIP_MEMORY_SCOPE_AGENT);
}

__global__ __launch_bounds__(256) void cvt_weights(
    const float* __restrict__ w0, const float* __restrict__ w1,
    const float* __restrict__ w2, const float* __restrict__ w3,
    short* __restrict__ out) {
  int i = blockIdx.x * 256 + threadIdx.x;
  if (i >= W_TOTAL) return;
  float v;
  if (i < OFF_WHH0)      v = w0[i - OFF_WIH0];
  else if (i < OFF_WIH1) v = w1[i - OFF_WHH0];
  else if (i < OFF_WHH1) v = w2[i - OFF_WIH1];
  else                   v = w3[i - OFF_WHH1];
  out[i] = f2bf(v);
}

__global__ __launch_bounds__(256) void init_state(unsigned* __restrict__ hz,
                                                  unsigned* __restrict__ flags) {
  int i = blockIdx.x * 256 + threadIdx.x;
  if (i < 2 * BB * HH) hz[i] = 0u;  // h1g+h2g = 4*B*H shorts = 2*B*H uints
  if (i < 16 * FLAG_STRIDE) flags[i] = 0u;
}

// 256 blocks = (bt 0..15) x (ht 0..15), 384 thr = 6 waves.
// Wave w: layer=w/3, gate=w%3; owns output cols [ht*16,ht*16+16); its weight
// B-fragments live in VGPRs for the whole kernel. Phase p computes h1[p] and
// h2[p-1]. Cross-block h exchange via sc1 (L2-bypassing) relaxed agent atomics
// -> no buffer_wbl2/buffer_inv cache maintenance anywhere.
__global__ __launch_bounds__(384) void gru_sync(
    const float* __restrict__ x, const short* __restrict__ wb,
    const float* __restrict__ bih0, const float* __restrict__ bhh0,
    const float* __restrict__ bih1, const float* __restrict__ bhh1,
    const float* __restrict__ Wfc, const float* __restrict__ bfc,
    short* __restrict__ h1g, short* __restrict__ h2g,
    unsigned* __restrict__ flags, float* __restrict__ out) {
  const int tid = threadIdx.x;
  const int lane = tid & 63;
  const int w = tid >> 6;
  const int quad = lane >> 4;
  const int col = lane & 15;
  const int bt = blockIdx.x & 15;
  const int ht = blockIdx.x >> 4;
  const int layer = w / 3, gate = w % 3;
  const int j = ht * 16 + col;

  __shared__ __align__(16) short ldsA[2][16][LDH];  // [0]=h1[p-1], [1]=h2[p-2]
  __shared__ __align__(16) float gt[2][6][16][20];  // [0]=IH acc, [1]=HH acc

  // ---- weights -> VGPRs (wave-uniform role) ----
  const short* wih = wb + (layer ? OFF_WIH1 : OFF_WIH0);
  const short* whh = wb + (layer ? OFF_WHH1 : OFF_WHH0);
  short8 wfI[8], wfH[8];
  if (layer == 0) {
#pragma unroll
    for (int f = 0; f < 4; ++f)
      wfI[f] = *(const short8*)(wih + (gate * HH + j) * II + f * 32 + quad * 8);
#pragma unroll
    for (int f = 4; f < 8; ++f) wfI[f] = short8{0, 0, 0, 0, 0, 0, 0, 0};
  } else {
#pragma unroll
    for (int f = 0; f < 8; ++f)
      wfI[f] = *(const short8*)(wih + (gate * HH + j) * HH + f * 32 + quad * 8);
  }
#pragma unroll
  for (int f = 0; f < 8; ++f)
    wfH[f] = *(const short8*)(whh + (gate * HH + j) * HH + f * 32 + quad * 8);

  const float* bihL = layer ? bih1 : bih0;
  const float* bhhL = layer ? bhh1 : bhh0;
  float bI, bH;
  if (gate == 2) { bI = bihL[2 * HH + j]; bH = bhhL[2 * HH + j]; }
  else { bI = bihL[gate * HH + j] + bhhL[gate * HH + j]; bH = 0.f; }

  // ---- elementwise roles: 2 adjacent cols per thread, stable over phases ----
  float h1a = 0.f, h1b = 0.f, h2a = 0.f, h2b = 0.f;
  const int r1 = tid >> 3, c1 = (tid & 7) * 2;              // tid < 128
  const int r2 = (tid - 256) >> 3, c2 = ((tid - 256) & 7) * 2;  // tid >= 256

  unsigned* cnt = flags + bt * FLAG_STRIDE;
  const size_t tbase = (size_t)(bt * 16) * HH;  // batch-tile base (shorts)

  for (int p = 0; p <= TT; ++p) {
    // x prefetch (independent of peers; L2-cached normal loads)
    short8 ax[4];
    if (w < 3 && p < TT) {
      const float* xr = x + ((size_t)p * BB + bt * 16 + col) * II + quad * 8;
#pragma unroll
      for (int f = 0; f < 4; ++f) ax[f] = cvt8(xr + f * 32);
    }

    if (p > 0) {
      if (tid == 0) {
        unsigned tgt = 16u * (unsigned)p;
        int guard = 0;
        while (__hip_atomic_load(cnt, __ATOMIC_RELAXED,
                                 __HIP_MEMORY_SCOPE_AGENT) < tgt &&
               guard < (1 << 20))
          ++guard;
      }
      __syncthreads();
    }

    // ---- stage peer tiles -> LDS via sc1 u64 loads (contiguous 8KB each) ----
    {
      const u64* s1 = (const u64*)(h1g + ((p + 1) & 1) * BB * HH + tbase);
      const u64* s2 = (const u64*)(h2g + (p & 1) * BB * HH + tbase);
      u64* d1 = (u64*)&ldsA[0][0][0];
      u64* d2 = (u64*)&ldsA[1][0][0];
      if (tid < 256) {
#pragma unroll
        for (int q = 0; q < 4; ++q) {
          int i = tid * 4 + q, row = i >> 6, c = i & 63;
          d1[row * (LDH / 4) + c] = ld_sc1(s1 + i);
        }
      }
      if (tid >= 128) {
        int t2 = tid - 128;
#pragma unroll
        for (int q = 0; q < 4; ++q) {
          int i = t2 * 4 + q, row = i >> 6, c = i & 63;
          d2[row * (LDH / 4) + c] = ld_sc1(s2 + i);
        }
      }
    }
    __syncthreads();

    // ---- MFMA (weights in regs, A frags from LDS) ----
    floatx4 aI = floatx4{bI, bI, bI, bI};
    floatx4 aH = floatx4{bH, bH, bH, bH};
    const short* a1 = &ldsA[0][col][0];
    const short* a2 = &ldsA[1][col][0];
    if (layer == 0) {
      if (p < TT) {
#pragma unroll
        for (int f = 0; f < 4; ++f)
          aI = __builtin_amdgcn_mfma_f32_16x16x32_bf16(ax[f], wfI[f], aI, 0, 0, 0);
      }
#pragma unroll
      for (int f = 0; f < 8; ++f) {
        short8 a = *(const short8*)(a1 + f * 32 + quad * 8);
        aH = __builtin_amdgcn_mfma_f32_16x16x32_bf16(a, wfH[f], aH, 0, 0, 0);
      }
    } else {
#pragma unroll
      for (int f = 0; f < 8; ++f) {
        short8 a = *(const short8*)(a1 + f * 32 + quad * 8);
        aI = __builtin_amdgcn_mfma_f32_16x16x32_bf16(a, wfI[f], aI, 0, 0, 0);
      }
#pragma unroll
      for (int f = 0; f < 8; ++f) {
        short8 a = *(const short8*)(a2 + f * 32 + quad * 8);
        aH = __builtin_amdgcn_mfma_f32_16x16x32_bf16(a, wfH[f], aH, 0, 0, 0);
      }
    }
#pragma unroll
    for (int i = 0; i < 4; ++i) {
      gt[0][w][quad * 4 + i][col] = aI[i];
      gt[1][w][quad * 4 + i][col] = aH[i];
    }
    __syncthreads();

    // ---- elementwise + publish (sc1 u32 stores, no dirty L2 lines) ----
    if (tid < 128 && p < TT) {
      float rA = fast_sigmoid(gt[0][0][r1][c1] + gt[1][0][r1][c1]);
      float zA = fast_sigmoid(gt[0][1][r1][c1] + gt[1][1][r1][c1]);
      float nA = fast_tanh(gt[0][2][r1][c1] + rA * gt[1][2][r1][c1]);
      h1a = nA + zA * (h1a - nA);
      float rB = fast_sigmoid(gt[0][0][r1][c1 + 1] + gt[1][0][r1][c1 + 1]);
      float zB = fast_sigmoid(gt[0][1][r1][c1 + 1] + gt[1][1][r1][c1 + 1]);
      float nB = fast_tanh(gt[0][2][r1][c1 + 1] + rB * gt[1][2][r1][c1 + 1]);
      h1b = nB + zB * (h1b - nB);
      unsigned val = ((unsigned)(unsigned short)f2bf(h1b) << 16) |
                     (unsigned)(unsigned short)f2bf(h1a);
      unsigned* dst = (unsigned*)(h1g + (p & 1) * BB * HH +
                                  (bt * 16 + r1) * HH + ht * 16 + c1);
      __hip_atomic_store(dst, val, __ATOMIC_RELAXED, __HIP_MEMORY_SCOPE_AGENT);
    }
    if (tid >= 256 && p > 0) {
      float rA = fast_sigmoid(gt[0][3][r2][c2] + gt[1][3][r2][c2]);
      float zA = fast_sigmoid(gt[0][4][r2][c2] + gt[1][4][r2][c2]);
      float nA = fast_tanh(gt[0][5][r2][c2] + rA * gt[1][5][r2][c2]);
      h2a = nA + zA * (h2a - nA);
      float rB = fast_sigmoid(gt[0][3][r2][c2 + 1] + gt[1][3][r2][c2 + 1]);
      float zB = fast_sigmoid(gt[0][4][r2][c2 + 1] + gt[1][4][r2][c2 + 1]);
      float nB = fast_tanh(gt[0][5][r2][c2 + 1] + rB * gt[1][5][r2][c2 + 1]);
      h2b = nB + zB * (h2b - nB);
      unsigned val = ((unsigned)(unsigned short)f2bf(h2b) << 16) |
                     (unsigned)(unsigned short)f2bf(h2a);
      unsigned* dst = (unsigned*)(h2g + ((p + 1) & 1) * BB * HH +
                                  (bt * 16 + r2) * HH + ht * 16 + c2);
      __hip_atomic_store(dst, val, __ATOMIC_RELAXED, __HIP_MEMORY_SCOPE_AGENT);
    }
    __syncthreads();  // vmcnt(0) drain: all sc1 publishes globally visible
    if (tid == 0)
      __hip_atomic_fetch_add(cnt, 1u, __ATOMIC_RELAXED,
                             __HIP_MEMORY_SCOPE_AGENT);
  }

  // ---- FC epilogue: out = h2[511] @ Wfc^T + bfc ----
  if (tid == 0) {
    unsigned tgt = 16u * (unsigned)(TT + 1);
    int guard = 0;
    while (__hip_atomic_load(cnt, __ATOMIC_RELAXED, __HIP_MEMORY_SCOPE_AGENT) <
               tgt &&
           guard < (1 << 20))
      ++guard;
  }
  __syncthreads();
  {
    const u64* s1 = (const u64*)(h2g + 1 * BB * HH + tbase);  // parity (TT+1)&1=1
    u64* d1 = (u64*)&ldsA[0][0][0];
    if (tid < 256) {
#pragma unroll
      for (int q = 0; q < 4; ++q) {
        int i = tid * 4 + q, row = i >> 6, c = i & 63;
        d1[row * (LDH / 4) + c] = ld_sc1(s1 + i);
      }
    }
  }
  __syncthreads();
  if (w == 0) {
    float bbv = bfc[j];
    floatx4 acc = floatx4{bbv, bbv, bbv, bbv};
#pragma unroll
    for (int f = 0; f < 8; ++f) {
      short8 a = *(const short8*)(&ldsA[0][col][0] + f * 32 + quad * 8);
      short8 bfrag = cvt8(Wfc + j * HH + f * 32 + quad * 8);
      acc = __builtin_amdgcn_mfma_f32_16x16x32_bf16(a, bfrag, acc, 0, 0, 0);
    }
#pragma unroll
    for (int i = 0; i < 4; ++i)
      out[(size_t)(bt * 16 + quad * 4 + i) * HH + j] = acc[i];
  }
}

extern "C" void kernel_launch(void* const* d_in, const int* in_sizes, int n_in,
                              void* d_out, int out_size, void* d_ws,
                              size_t ws_size, hipStream_t stream) {
  const float* x = (const float*)d_in[0];
  const float* Wih0 = (const float*)d_in[1];
  const float* Whh0 = (const float*)d_in[2];
  const float* bih0 = (const float*)d_in[3];
  const float* bhh0 = (const float*)d_in[4];
  const float* Wih1 = (const float*)d_in[5];
  const float* Whh1 = (const float*)d_in[6];
  const float* bih1 = (const float*)d_in[7];
  const float* bhh1 = (const float*)d_in[8];
  const float* Wfc = (const float*)d_in[9];
  const float* bfc = (const float*)d_in[10];

  short* wb = (short*)d_ws;
  short* h1g = wb + H1G_OFF;
  short* h2g = wb + H2G_OFF;
  unsigned* flags = (unsigned*)((char*)d_ws + FLAGS_OFF_BYTES);
  unsigned* hz = (unsigned*)(wb + H1G_OFF);

  cvt_weights<<<(W_TOTAL + 255) / 256, 256, 0, stream>>>(Wih0, Whh0, Wih1, Whh1, wb);
  init_state<<<(2 * BB * HH + 255) / 256, 256, 0, stream>>>(hz, flags);
  gru_sync<<<256, 384, 0, stream>>>(x, wb, bih0, bhh0, bih1, bhh1, Wfc, bfc,
                                    h1g, h2g, flags, (float*)d_out);
}